// Round 11
// baseline (736.973 us; speedup 1.0000x reference)
//
#include <hip/hip_runtime.h>
#include <hip/hip_bf16.h>
#include <stdint.h>

#define NOUT 11008
#define KIN  4096
#define MTOK 4096
#define PLD  5504            // int32 elements per k-row of pw
#define NSTEP 128            // K-tiles of 32
#define NTN 43               // 11008 / 256
#define NTM 16               // 4096 / 256
#define ACHUNK 16384         // 256 rows x 32k x 2B (bf16 A image)
#define BCH    6144          // packed-B chunk: 4KB nibbles + 1KB scales + 1KB pad
#define WSA_BYTES ((size_t)NTM * NSTEP * ACHUNK)   // 32 MB
#define WSB_BYTES ((size_t)NTN * NSTEP * BCH)      // 33.8 MB

typedef short bf16x8 __attribute__((ext_vector_type(8)));
typedef float f32x4  __attribute__((ext_vector_type(4)));

typedef __attribute__((address_space(3))) uint8_t lds_u8_t;
typedef __attribute__((address_space(1))) const uint8_t glb_u8_t;

__device__ __forceinline__ uint32_t bfpack(float lo, float hi){
    __hip_bfloat16 a = __float2bfloat16(lo);
    __hip_bfloat16 b = __float2bfloat16(hi);
    uint16_t ua, ub;
    __builtin_memcpy(&ua, &a, 2);
    __builtin_memcpy(&ub, &b, 2);
    return (uint32_t)ua | ((uint32_t)ub << 16);
}

__device__ __forceinline__ int swzA(int r){ return ((r >> 1) & 3) << 4; }

// decode 8 nibbles (one col, 8 consecutive k) -> dequantized bf16x8  [bit-exact per r6]
__device__ __forceinline__ bf16x8 decodeFrag(uint2 w, uint32_t sh, float s, float m8s)
{
    uint32_t a = (w.x >> sh) & 0x0f0f0f0fu;
    uint32_t b = (w.y >> sh) & 0x0f0f0f0fu;
    float d0 = fmaf((float)(a & 0xffu),         s, m8s);
    float d1 = fmaf((float)((a >> 8) & 0xffu),  s, m8s);
    float d2 = fmaf((float)((a >> 16) & 0xffu), s, m8s);
    float d3 = fmaf((float)(a >> 24),           s, m8s);
    float d4 = fmaf((float)(b & 0xffu),         s, m8s);
    float d5 = fmaf((float)((b >> 8) & 0xffu),  s, m8s);
    float d6 = fmaf((float)((b >> 16) & 0xffu), s, m8s);
    float d7 = fmaf((float)(b >> 24),           s, m8s);
    uint32_t r[4] = { bfpack(d0, d1), bfpack(d2, d3), bfpack(d4, d5), bfpack(d6, d7) };
    bf16x8 out;
    __builtin_memcpy(&out, r, 16);
    return out;
}

// ---------------- pre-pass A: x fp32 -> bf16, [mt][t][m 0..255][64B k-stripe swz] (r8 exact) ----------------
__global__ __launch_bounds__(256)
void prepA(const float* __restrict__ x, uint8_t* __restrict__ wsA)
{
    int gid = blockIdx.x * 256 + threadIdx.x;
    int m  = gid >> 10;
    int k  = (gid & 1023) << 2;
    float4 v = *reinterpret_cast<const float4*>(x + (size_t)m * KIN + k);
    uint32_t lo = bfpack(v.x, v.y), hi = bfpack(v.z, v.w);
    int mt = m >> 8, ml = m & 255, t = k >> 5, kl = k & 31;
    size_t dst = (size_t)(mt * NSTEP + t) * ACHUNK + ml * 64 + ((kl * 2) ^ swzA(ml));
    *reinterpret_cast<uint2*>(wsA + dst) = make_uint2(lo, hi);
}

// ---------------- pre-pass B: packed-nibble LDS-image + scales, k-transposed ----------------
// chunk (nt,t): [np 0..127][32B: bytes k=0..31, 8B-groups XOR-swz] ++ [4096+col*4: scale f32]
__global__ __launch_bounds__(256)
void prepB3(const int32_t* __restrict__ pw, const float* __restrict__ sc,
            uint8_t* __restrict__ wsB)
{
    const int t  = blockIdx.x;                 // 0..127
    const int nt = blockIdx.y;                 // 0..42
    const int tid = threadIdx.x;
    uint8_t* out = wsB + ((size_t)nt * NSTEP + t) * BCH;
    if (tid < 128) {
        const int np = tid;
        const int32_t* p = pw + (size_t)(t * 32) * PLD + nt * 128 + np;
#pragma unroll
        for (int g = 0; g < 4; ++g) {
            uint64_t v = 0;
#pragma unroll
            for (int i = 0; i < 8; ++i)
                v |= (uint64_t)((uint32_t)p[(size_t)(g * 8 + i) * PLD] & 0xFFu) << (8 * i);
            *reinterpret_cast<uint64_t*>(out + np * 32 + ((g * 8) ^ ((np & 3) * 8))) = v;
        }
    } else {
        const int c2 = tid - 128;              // two cols per thread
        float2 s = *reinterpret_cast<const float2*>(sc + (size_t)(t >> 2) * NOUT + nt * 256 + 2 * c2);
        *reinterpret_cast<float2*>(out + 4096 + 8 * c2) = s;
    }
}

// ---------------- main GEMM: r8 skeleton, packed-B in-read decode ----------------
__global__ __launch_bounds__(512, 1)
void qlin_gemm11(const uint8_t* __restrict__ wsA, const uint8_t* __restrict__ wsB,
                 const float* __restrict__ bias, float* __restrict__ y)
{
    __shared__ __align__(16) uint8_t ldsA[4][ACHUNK];   // 64 KB
    __shared__ __align__(16) uint8_t ldsB[4][BCH];      // 24 KB

    const int tid  = threadIdx.x;
    const int lane = tid & 63;
    const int wid  = tid >> 6;
    const int wr = wid >> 2, wc = wid & 3;   // 2x4 wave grid, 128x64 per wave

    const int lb = (blockIdx.x & 7) * 86 + (blockIdx.x >> 3);  // bijective XCD swizzle (688 = 8*86)
    const int mt = lb / NTN, nt = lb % NTN;
    const int m0 = mt * 256, n0 = nt * 256;

    const int cl = lane & 15;
    const int k8 = lane >> 4;
    const uint32_t sh4 = (uint32_t)(cl & 1) * 4;

    int aOff[8];
#pragma unroll
    for (int i = 0; i < 8; ++i) {
        int ml = wr * 128 + i * 16 + cl;
        aOff[i] = ml * 64 + ((k8 * 16) ^ swzA(ml));
    }
    int bpOff[4], scOff[4];
#pragma unroll
    for (int j = 0; j < 4; ++j) {
        int col = wc * 64 + j * 16 + cl;
        int np  = col >> 1;
        bpOff[j] = np * 32 + ((k8 * 8) ^ ((np & 3) * 8));
        scOff[j] = 4096 + col * 4;
    }

    const uint8_t* wsAbase = wsA + (size_t)mt * NSTEP * ACHUNK;
    const uint8_t* wsBbase = wsB + (size_t)nt * NSTEP * BCH;

    f32x4 acc[8][4];
#pragma unroll
    for (int i = 0; i < 8; ++i)
#pragma unroll
        for (int j = 0; j < 4; ++j)
            acc[i][j] = (f32x4){0.f, 0.f, 0.f, 0.f};

    bf16x8 AF[4], BF[4];

#define STAGE_A(buf, t) do { \
    const uint8_t* gA_ = wsAbase + (size_t)(t) * ACHUNK + tid * 16; \
    __builtin_amdgcn_global_load_lds((glb_u8_t*)(gA_),        (lds_u8_t*)(&ldsA[buf][tid*16]),        16, 0, 0); \
    __builtin_amdgcn_global_load_lds((glb_u8_t*)(gA_ + 8192), (lds_u8_t*)(&ldsA[buf][tid*16 + 8192]), 16, 0, 0); \
} while(0)

#define STAGE_B(buf, t) do { \
    const uint8_t* gB_ = wsBbase + (size_t)(t) * BCH + tid * 4; \
    __builtin_amdgcn_global_load_lds((glb_u8_t*)(gB_),        (lds_u8_t*)(&ldsB[buf][tid*4]),        4, 0, 0); \
    __builtin_amdgcn_global_load_lds((glb_u8_t*)(gB_ + 2048), (lds_u8_t*)(&ldsB[buf][tid*4 + 2048]), 4, 0, 0); \
    __builtin_amdgcn_global_load_lds((glb_u8_t*)(gB_ + 4096), (lds_u8_t*)(&ldsB[buf][tid*4 + 4096]), 4, 0, 0); \
} while(0)

#define BAR() do { \
    asm volatile("" ::: "memory"); \
    __builtin_amdgcn_s_barrier(); \
    asm volatile("" ::: "memory"); \
} while(0)

    // odd phase: stage A(next); read B-packed+scales then A-lo; decode under A-read; MFMA m-half 0
#define PH_O(cb, sb, st) do { \
    STAGE_A(sb, st); \
    uint2 braw_[4]; float ss_[4]; \
    _Pragma("unroll") \
    for (int j = 0; j < 4; ++j) braw_[j] = *reinterpret_cast<const uint2*>(ldsB[cb] + bpOff[j]); \
    _Pragma("unroll") \
    for (int j = 0; j < 4; ++j) ss_[j] = *reinterpret_cast<const float*>(ldsB[cb] + scOff[j]); \
    __builtin_amdgcn_sched_barrier(0); \
    _Pragma("unroll") \
    for (int i = 0; i < 4; ++i) AF[i] = *reinterpret_cast<const bf16x8*>(ldsA[cb] + aOff[i]); \
    BAR(); \
    asm volatile("s_waitcnt lgkmcnt(4)" ::: "memory"); \
    __builtin_amdgcn_sched_barrier(0); \
    _Pragma("unroll") \
    for (int j = 0; j < 4; ++j) BF[j] = decodeFrag(braw_[j], sh4, ss_[j], -8.f * ss_[j]); \
    asm volatile("s_waitcnt lgkmcnt(0)" ::: "memory"); \
    __builtin_amdgcn_sched_barrier(0); \
    __builtin_amdgcn_s_setprio(1); \
    _Pragma("unroll") \
    for (int j = 0; j < 4; ++j) { _Pragma("unroll") \
        for (int i = 0; i < 4; ++i) \
            acc[i][j] = __builtin_amdgcn_mfma_f32_16x16x32_bf16(AF[i], BF[j], acc[i][j], 0, 0, 0); } \
    __builtin_amdgcn_s_setprio(0); \
    BAR(); \
} while(0)

    // even phase: stage B(next); read A-hi; MFMA m-half 1 (BF held); counted vmcnt
#define PH_E(cb, sb, st) do { \
    STAGE_B(sb, st); \
    _Pragma("unroll") \
    for (int i = 0; i < 4; ++i) AF[i] = *reinterpret_cast<const bf16x8*>(ldsA[cb] + aOff[4 + i]); \
    BAR(); \
    asm volatile("s_waitcnt lgkmcnt(0)" ::: "memory"); \
    __builtin_amdgcn_sched_barrier(0); \
    __builtin_amdgcn_s_setprio(1); \
    _Pragma("unroll") \
    for (int j = 0; j < 4; ++j) { _Pragma("unroll") \
        for (int i = 0; i < 4; ++i) \
            acc[4 + i][j] = __builtin_amdgcn_mfma_f32_16x16x32_bf16(AF[i], BF[j], acc[4 + i][j], 0, 0, 0); } \
    __builtin_amdgcn_s_setprio(0); \
    asm volatile("s_waitcnt vmcnt(10)" ::: "memory"); \
    __builtin_amdgcn_sched_barrier(0); \
    BAR(); \
} while(0)

    // ---- prologue: stage tiles 0,1,2 into bufs 0,1,2 (5 loads each) ----
    STAGE_A(0, 0); STAGE_B(0, 0);
    STAGE_A(1, 1); STAGE_B(1, 1);
    STAGE_A(2, 2); STAGE_B(2, 2);
    asm volatile("s_waitcnt vmcnt(10)" ::: "memory");   // tile 0 landed
    __builtin_amdgcn_sched_barrier(0);
    BAR();

    // ---- main loop: 32 iterations x 4 K-tiles x 2 phases (r8 schedule) ----
#pragma unroll 1
    for (int tb = 0; tb < NSTEP; tb += 4) {
        const int s4 = (tb + 4 < NSTEP) ? tb + 4 : NSTEP - 1;
        const int s5 = (tb + 5 < NSTEP) ? tb + 5 : NSTEP - 1;
        const int s6 = (tb + 6 < NSTEP) ? tb + 6 : NSTEP - 1;
        PH_O(0, 3, tb + 3);  PH_E(0, 3, tb + 3);
        PH_O(1, 0, s4);      PH_E(1, 0, s4);
        PH_O(2, 1, s5);      PH_E(2, 1, s5);
        PH_O(3, 2, s6);      PH_E(3, 2, s6);
    }

    // ---- epilogue: acc + bias -> y (C/D: col=lane&15, row=(lane>>4)*4+reg) ----
    float bv[4];
#pragma unroll
    for (int j = 0; j < 4; ++j) bv[j] = bias[n0 + wc * 64 + j * 16 + cl];
    const int rg = (lane >> 4) * 4;
#pragma unroll
    for (int i = 0; i < 8; ++i) {
        const int mrow = m0 + wr * 128 + i * 16 + rg;
#pragma unroll
        for (int r = 0; r < 4; ++r) {
            float* yp = y + (size_t)(mrow + r) * NOUT + n0 + wc * 64 + cl;
#pragma unroll
            for (int j = 0; j < 4; ++j)
                yp[j * 16] = acc[i][j][r] + bv[j];
        }
    }

#undef STAGE_A
#undef STAGE_B
#undef BAR
#undef PH_O
#undef PH_E
}

extern "C" void kernel_launch(void* const* d_in, const int* in_sizes, int n_in,
                              void* d_out, int out_size, void* d_ws, size_t ws_size,
                              hipStream_t stream)
{
    const float*   xin  = (const float*)d_in[0];
    const int32_t* pw   = (const int32_t*)d_in[1];   // harness pushes int8 as int32
    const float*   scal = (const float*)d_in[2];
    const float*   bias = (const float*)d_in[3];
    float* y = (float*)d_out;

    uint8_t* wsA = (uint8_t*)d_ws;
    uint8_t* wsB = wsA + WSA_BYTES;                  // 32 + 33.8 MB << ws (>=124 MB proven r7)

    prepA<<<dim3((MTOK * (KIN / 4)) / 256), 256, 0, stream>>>(xin, wsA);
    prepB3<<<dim3(NSTEP, NTN), 256, 0, stream>>>(pw, scal, wsB);
    qlin_gemm11<<<dim3(NTM * NTN), 512, 0, stream>>>(wsA, wsB, bias, y);
}

// Round 12
// 416.311 us; speedup vs baseline: 1.7702x; 1.7702x over previous
//
#include <hip/hip_runtime.h>
#include <hip/hip_bf16.h>
#include <stdint.h>

#define NOUT 11008
#define KIN  4096
#define MTOK 4096
#define PLD  5504            // int32 elements per k-row of pw
#define NSTEP 128            // K-tiles of 32
#define NTN 43               // 11008 / 256
#define NTM 16               // 4096 / 256
#define ACHUNK 16384         // 256 rows x 32k x 2B
#define BCHUNK 16384         // 256 cols x 32k x 2B
#define WSA_BYTES ((size_t)NTM * NSTEP * ACHUNK)   // 32 MB
#define WSW_BYTES ((size_t)NTN * NSTEP * BCHUNK)   // 90.2 MB

typedef short bf16x8 __attribute__((ext_vector_type(8)));
typedef float f32x4  __attribute__((ext_vector_type(4)));

typedef __attribute__((address_space(3))) uint8_t lds_u8_t;
typedef __attribute__((address_space(1))) const uint8_t glb_u8_t;

__device__ __forceinline__ uint32_t bfpack(float lo, float hi){
    __hip_bfloat16 a = __float2bfloat16(lo);
    __hip_bfloat16 b = __float2bfloat16(hi);
    uint16_t ua, ub;
    __builtin_memcpy(&ua, &a, 2);
    __builtin_memcpy(&ub, &b, 2);
    return (uint32_t)ua | ((uint32_t)ub << 16);
}

__device__ __forceinline__ int swzA(int r){ return ((r >> 1) & 3) << 4; }

// ---------------- pre-pass A: x fp32 -> bf16, [mt][t][m 0..255][64B k-stripe swz] (r8 exact) ----------------
__global__ __launch_bounds__(256)
void prepA(const float* __restrict__ x, uint8_t* __restrict__ wsA)
{
    int gid = blockIdx.x * 256 + threadIdx.x;
    int m  = gid >> 10;
    int k  = (gid & 1023) << 2;
    float4 v = *reinterpret_cast<const float4*>(x + (size_t)m * KIN + k);
    uint32_t lo = bfpack(v.x, v.y), hi = bfpack(v.z, v.w);
    int mt = m >> 8, ml = m & 255, t = k >> 5, kl = k & 31;
    size_t dst = (size_t)(mt * NSTEP + t) * ACHUNK + ml * 64 + ((kl * 2) ^ swzA(ml));
    *reinterpret_cast<uint2*>(wsA + dst) = make_uint2(lo, hi);
}

// ---------------- pre-pass W: dequant int4 -> bf16 chunks [nt][t][col 0..255][64B swz] (r8 exact) ----------------
__global__ __launch_bounds__(256)
void prepW2(const int32_t* __restrict__ pw, const float* __restrict__ sc,
            uint8_t* __restrict__ wsW)
{
    const int t  = blockIdx.x;
    const int nt = blockIdx.y;
    const int c  = threadIdx.x;
    const int col = nt * 256 + c;
    const int np  = col >> 1;
    const uint32_t sh = (uint32_t)(col & 1) * 4;
    const int32_t* p = pw + (size_t)(t * 32) * PLD + np;
    const float s  = sc[(size_t)(t >> 2) * NOUT + col];
    const float m8 = -8.f * s;
    uint8_t* out = wsW + ((size_t)nt * NSTEP + t) * BCHUNK + c * 64;
#pragma unroll
    for (int k8 = 0; k8 < 4; ++k8) {
        uint32_t r[4];
#pragma unroll
        for (int kk = 0; kk < 4; ++kk) {
            uint32_t w0 = (uint32_t)p[(size_t)(k8 * 8 + kk * 2)     * PLD];
            uint32_t w1 = (uint32_t)p[(size_t)(k8 * 8 + kk * 2 + 1) * PLD];
            float f0 = fmaf((float)((w0 >> sh) & 15u), s, m8);
            float f1 = fmaf((float)((w1 >> sh) & 15u), s, m8);
            r[kk] = bfpack(f0, f1);
        }
        *reinterpret_cast<uint4*>(out + ((k8 * 16) ^ swzA(c))) = *reinterpret_cast<uint4*>(r);
    }
}

// ---------------- main GEMM: r8 skeleton; compiler-scheduled lgkm (drain fence removed) ----------------
__global__ __launch_bounds__(512, 1)
void qlin_gemm12(const uint8_t* __restrict__ wsA, const uint8_t* __restrict__ wsW,
                 const float* __restrict__ bias, float* __restrict__ y)
{
    __shared__ __align__(16) uint8_t ldsA[4][ACHUNK];   // 64 KB
    __shared__ __align__(16) uint8_t ldsB[4][BCHUNK];   // 64 KB

    const int tid  = threadIdx.x;
    const int lane = tid & 63;
    const int wid  = tid >> 6;
    const int wr = wid >> 2, wc = wid & 3;   // 2x4 wave grid, 128x64 per wave

    const int lb = (blockIdx.x & 7) * 86 + (blockIdx.x >> 3);  // bijective XCD swizzle (688 = 8*86)
    const int mt = lb / NTN, nt = lb % NTN;
    const int m0 = mt * 256, n0 = nt * 256;

    const int cl = lane & 15;
    const int k8 = lane >> 4;

    int aOff[8];
#pragma unroll
    for (int i = 0; i < 8; ++i) {
        int ml = wr * 128 + i * 16 + cl;
        aOff[i] = ml * 64 + ((k8 * 16) ^ swzA(ml));
    }
    int bOff[4];
#pragma unroll
    for (int j = 0; j < 4; ++j) {
        int cc = wc * 64 + j * 16 + cl;
        bOff[j] = cc * 64 + ((k8 * 16) ^ swzA(cc));
    }

    const uint8_t* wsAbase = wsA + (size_t)mt * NSTEP * ACHUNK;
    const uint8_t* wsWbase = wsW + (size_t)nt * NSTEP * BCHUNK;

    f32x4 acc[8][4];
#pragma unroll
    for (int i = 0; i < 8; ++i)
#pragma unroll
        for (int j = 0; j < 4; ++j)
            acc[i][j] = (f32x4){0.f, 0.f, 0.f, 0.f};

    bf16x8 af[4], bfr[4];

#define STAGE_A(buf, t) do { \
    const uint8_t* g_ = wsAbase + (size_t)(t) * ACHUNK + tid * 16; \
    __builtin_amdgcn_global_load_lds((glb_u8_t*)(g_),        (lds_u8_t*)(&ldsA[buf][tid*16]),        16, 0, 0); \
    __builtin_amdgcn_global_load_lds((glb_u8_t*)(g_ + 8192), (lds_u8_t*)(&ldsA[buf][tid*16 + 8192]), 16, 0, 0); \
} while(0)

#define STAGE_B(buf, t) do { \
    const uint8_t* g_ = wsWbase + (size_t)(t) * BCHUNK + tid * 16; \
    __builtin_amdgcn_global_load_lds((glb_u8_t*)(g_),        (lds_u8_t*)(&ldsB[buf][tid*16]),        16, 0, 0); \
    __builtin_amdgcn_global_load_lds((glb_u8_t*)(g_ + 8192), (lds_u8_t*)(&ldsB[buf][tid*16 + 8192]), 16, 0, 0); \
} while(0)

#define BAR() do { \
    asm volatile("" ::: "memory"); \
    __builtin_amdgcn_s_barrier(); \
    asm volatile("" ::: "memory"); \
} while(0)

    // odd phase: stage next A; read frags (m-half 0); MFMA with compiler-scheduled lgkm waits
#define PH_O(cb, sb, st) do { \
    STAGE_A(sb, st); \
    _Pragma("unroll") \
    for (int i = 0; i < 4; ++i) { \
        af[i]  = *reinterpret_cast<const bf16x8*>(ldsA[cb] + aOff[i]); \
        bfr[i] = *reinterpret_cast<const bf16x8*>(ldsB[cb] + bOff[i]); \
    } \
    BAR(); \
    __builtin_amdgcn_s_setprio(1); \
    _Pragma("unroll") \
    for (int j = 0; j < 4; ++j) { _Pragma("unroll") \
        for (int i = 0; i < 4; ++i) \
            acc[i][j] = __builtin_amdgcn_mfma_f32_16x16x32_bf16(af[i], bfr[j], acc[i][j], 0, 0, 0); } \
    __builtin_amdgcn_s_setprio(0); \
    BAR(); \
} while(0)

    // even phase: stage next B; read A m-half 1 (bfr held); MFMA; counted vmcnt drain
#define PH_E(cb, sb, st) do { \
    STAGE_B(sb, st); \
    _Pragma("unroll") \
    for (int i = 0; i < 4; ++i) af[i] = *reinterpret_cast<const bf16x8*>(ldsA[cb] + aOff[4 + i]); \
    BAR(); \
    __builtin_amdgcn_s_setprio(1); \
    _Pragma("unroll") \
    for (int j = 0; j < 4; ++j) { _Pragma("unroll") \
        for (int i = 0; i < 4; ++i) \
            acc[4 + i][j] = __builtin_amdgcn_mfma_f32_16x16x32_bf16(af[i], bfr[j], acc[4 + i][j], 0, 0, 0); } \
    __builtin_amdgcn_s_setprio(0); \
    asm volatile("s_waitcnt vmcnt(8)" ::: "memory"); \
    __builtin_amdgcn_sched_barrier(0); \
    BAR(); \
} while(0)

    // ---- prologue: stage tiles 0,1,2 into bufs 0,1,2 ----
    STAGE_A(0, 0); STAGE_B(0, 0);
    STAGE_A(1, 1); STAGE_B(1, 1);
    STAGE_A(2, 2); STAGE_B(2, 2);
    asm volatile("s_waitcnt vmcnt(8)" ::: "memory");   // tile 0 landed
    __builtin_amdgcn_sched_barrier(0);
    BAR();

    // ---- main loop: 32 iterations x 4 K-tiles x 2 phases (r8 schedule) ----
#pragma unroll 1
    for (int tb = 0; tb < NSTEP; tb += 4) {
        const int s4 = (tb + 4 < NSTEP) ? tb + 4 : NSTEP - 1;
        const int s5 = (tb + 5 < NSTEP) ? tb + 5 : NSTEP - 1;
        const int s6 = (tb + 6 < NSTEP) ? tb + 6 : NSTEP - 1;
        PH_O(0, 3, tb + 3);  PH_E(0, 3, tb + 3);
        PH_O(1, 0, s4);      PH_E(1, 0, s4);
        PH_O(2, 1, s5);      PH_E(2, 1, s5);
        PH_O(3, 2, s6);      PH_E(3, 2, s6);
    }

    // ---- epilogue: acc + bias -> y (C/D: col=lane&15, row=(lane>>4)*4+reg) ----
    float bv[4];
#pragma unroll
    for (int j = 0; j < 4; ++j) bv[j] = bias[n0 + wc * 64 + j * 16 + cl];
    const int rg = (lane >> 4) * 4;
#pragma unroll
    for (int i = 0; i < 8; ++i) {
        const int mrow = m0 + wr * 128 + i * 16 + rg;
#pragma unroll
        for (int r = 0; r < 4; ++r) {
            float* yp = y + (size_t)(mrow + r) * NOUT + n0 + wc * 64 + cl;
#pragma unroll
            for (int j = 0; j < 4; ++j)
                yp[j * 16] = acc[i][j][r] + bv[j];
        }
    }

#undef STAGE_A
#undef STAGE_B
#undef BAR
#undef PH_O
#undef PH_E
}

extern "C" void kernel_launch(void* const* d_in, const int* in_sizes, int n_in,
                              void* d_out, int out_size, void* d_ws, size_t ws_size,
                              hipStream_t stream)
{
    const float*   xin  = (const float*)d_in[0];
    const int32_t* pw   = (const int32_t*)d_in[1];   // harness pushes int8 as int32
    const float*   scal = (const float*)d_in[2];
    const float*   bias = (const float*)d_in[3];
    float* y = (float*)d_out;

    uint8_t* wsA = (uint8_t*)d_ws;
    uint8_t* wsW = wsA + WSA_BYTES;

    prepA<<<dim3((MTOK * (KIN / 4)) / 256), 256, 0, stream>>>(xin, wsA);
    prepW2<<<dim3(NSTEP, NTN), 256, 0, stream>>>(pw, scal, wsW);
    qlin_gemm12<<<dim3(NTM * NTN), 512, 0, stream>>>(wsA, wsW, bias, y);
}